// Round 4
// baseline (98.993 us; speedup 1.0000x reference)
//
#include <hip/hip_runtime.h>

// Statevector shape: (2,)*24 + (4,), float32, row-major.
// TARGET qubit = 11 -> element stride = 16384 floats = 4096 float4s.
// Total: 2^24 * 4 = 67108864 floats = 16777216 float4s = 8388608 float4-pairs.
//
// out[i0] = p00*s[i0] + p01*s[i1];  out[i1] = p10*s[i0] + p11*s[i1]
//
// Pure streaming (read-once/write-once): non-temporal loads/stores bypass L2
// allocate. Each thread handles 4 pairs (tid + k*NPAIRS/4), giving 8 loads +
// 8 stores in flight per thread across 8 distinct 1KiB wave-streams.

typedef float f32x4 __attribute__((ext_vector_type(4)));

#define NPAIRS4 8388608

__global__ __launch_bounds__(256) void pauli_apply_kernel(
    const f32x4* __restrict__ state,
    const float* __restrict__ pauli,
    f32x4* __restrict__ out) {
    const int tid = blockIdx.x * blockDim.x + threadIdx.x;  // [0, NPAIRS4/4)

    const float p00 = pauli[0];
    const float p01 = pauli[1];
    const float p10 = pauli[2];
    const float p11 = pauli[3];

    int a[4], b[4];
#pragma unroll
    for (int k = 0; k < 4; ++k) {
        const int t = tid + k * (NPAIRS4 / 4);
        const int g = t >> 12, w = t & 4095;
        a[k] = (g << 13) + w;
        b[k] = a[k] + 4096;
    }

    f32x4 sA[4], sB[4];
#pragma unroll
    for (int k = 0; k < 4; ++k) {
        sA[k] = __builtin_nontemporal_load(&state[a[k]]);
        sB[k] = __builtin_nontemporal_load(&state[b[k]]);
    }

#pragma unroll
    for (int k = 0; k < 4; ++k) {
        const f32x4 oA = p00 * sA[k] + p01 * sB[k];
        const f32x4 oB = p10 * sA[k] + p11 * sB[k];
        __builtin_nontemporal_store(oA, &out[a[k]]);
        __builtin_nontemporal_store(oB, &out[b[k]]);
    }
}

extern "C" void kernel_launch(void* const* d_in, const int* in_sizes, int n_in,
                              void* d_out, int out_size, void* d_ws, size_t ws_size,
                              hipStream_t stream) {
    const f32x4* state = (const f32x4*)d_in[0];
    const float* pauli = (const float*)d_in[1];
    f32x4*       out   = (f32x4*)d_out;

    const int nthreads = NPAIRS4 / 4;  // 2097152
    const int block = 256;
    const int grid = nthreads / block;  // 8192

    pauli_apply_kernel<<<grid, block, 0, stream>>>(state, pauli, out);
}

// Round 5
// 96.221 us; speedup vs baseline: 1.0288x; 1.0288x over previous
//
#include <hip/hip_runtime.h>

// Statevector shape: (2,)*24 + (4,), float32, row-major.
// TARGET qubit = 11 -> element stride = 16384 floats = 4096 float4s.
// Total: 2^24 * 4 = 67108864 floats = 16777216 float4s = 8388608 float4-pairs.
//
// out[i0] = p00*s[i0] + p01*s[i1];  out[i1] = p10*s[i0] + p11*s[i1]
//
// Pure streaming: non-temporal loads/stores (zero reuse; in+out = 512 MiB
// thrashes the 32 MiB L2 / 256 MiB L3). Each thread handles 2 ADJACENT
// float4 pairs -> each lane does one 32 B chunk per stream; a wave covers
// two contiguous 2 KiB load regions + the same two store regions.

typedef float f32x4 __attribute__((ext_vector_type(4)));

#define NPAIRS4 8388608

__global__ __launch_bounds__(256) void pauli_apply_kernel(
    const f32x4* __restrict__ state,
    const float* __restrict__ pauli,
    f32x4* __restrict__ out) {
    const int tid = blockIdx.x * blockDim.x + threadIdx.x;  // [0, NPAIRS4/2)

    const float p00 = pauli[0];
    const float p01 = pauli[1];
    const float p10 = pauli[2];
    const float p11 = pauli[3];

    // group = tid / 2048 (axis-11 upper index), within-group float4 offset
    // = 2*(tid % 2048). Group spans 8192 float4s (2 halves of 4096).
    const int g = tid >> 11;
    const int w = (tid & 2047) << 1;
    const int a = (g << 13) + w;     // first float4 of the a-side 32B chunk
    const int b = a + 4096;          // matching b-side chunk

    const f32x4 sA0 = __builtin_nontemporal_load(&state[a]);
    const f32x4 sA1 = __builtin_nontemporal_load(&state[a + 1]);
    const f32x4 sB0 = __builtin_nontemporal_load(&state[b]);
    const f32x4 sB1 = __builtin_nontemporal_load(&state[b + 1]);

    const f32x4 oA0 = p00 * sA0 + p01 * sB0;
    const f32x4 oA1 = p00 * sA1 + p01 * sB1;
    const f32x4 oB0 = p10 * sA0 + p11 * sB0;
    const f32x4 oB1 = p10 * sA1 + p11 * sB1;

    __builtin_nontemporal_store(oA0, &out[a]);
    __builtin_nontemporal_store(oA1, &out[a + 1]);
    __builtin_nontemporal_store(oB0, &out[b]);
    __builtin_nontemporal_store(oB1, &out[b + 1]);
}

extern "C" void kernel_launch(void* const* d_in, const int* in_sizes, int n_in,
                              void* d_out, int out_size, void* d_ws, size_t ws_size,
                              hipStream_t stream) {
    const f32x4* state = (const f32x4*)d_in[0];
    const float* pauli = (const float*)d_in[1];
    f32x4*       out   = (f32x4*)d_out;

    const int nthreads = NPAIRS4 / 2;  // 4194304
    const int block = 256;
    const int grid = nthreads / block;  // 16384

    pauli_apply_kernel<<<grid, block, 0, stream>>>(state, pauli, out);
}

// Round 6
// 91.966 us; speedup vs baseline: 1.0764x; 1.0463x over previous
//
#include <hip/hip_runtime.h>

// Statevector shape: (2,)*24 + (4,), float32, row-major.
// TARGET qubit = 11 -> element stride = 16384 floats = 4096 float4s.
// Total: 2^24 * 4 = 67108864 floats = 16777216 float4s = 8388608 float4-pairs.
//
// out[i0] = p00*s[i0] + p01*s[i1];  out[i1] = p10*s[i0] + p11*s[i1]
//
// Pure streaming (read-once/write-once): non-temporal hints bypass L2
// allocate. Each thread handles 2 pairs (tid and tid + NPAIRS/2) for ILP.
// Empirical optimum (round 3: 91.5 us = 5.87 TB/s, 93% of copy ceiling):
//  - deeper ILP (4 pairs/thread, half grid) regressed to 99.0 us
//  - adjacent-pair layout regressed to 96.2 us

typedef float f32x4 __attribute__((ext_vector_type(4)));

#define NPAIRS4 8388608

__global__ __launch_bounds__(256) void pauli_apply_kernel(
    const f32x4* __restrict__ state,
    const float* __restrict__ pauli,
    f32x4* __restrict__ out) {
    const int tid = blockIdx.x * blockDim.x + threadIdx.x;  // [0, NPAIRS4/2)

    const float p00 = pauli[0];
    const float p01 = pauli[1];
    const float p10 = pauli[2];
    const float p11 = pauli[3];

    const int t0 = tid;
    const int t1 = tid + (NPAIRS4 / 2);

    // pair index -> (idx0, idx1) in float4 units
    const int g0 = t0 >> 12, w0 = t0 & 4095;
    const int a0 = (g0 << 13) + w0, b0 = a0 + 4096;
    const int g1 = t1 >> 12, w1 = t1 & 4095;
    const int a1 = (g1 << 13) + w1, b1 = a1 + 4096;

    const f32x4 sA0 = __builtin_nontemporal_load(&state[a0]);
    const f32x4 sB0 = __builtin_nontemporal_load(&state[b0]);
    const f32x4 sA1 = __builtin_nontemporal_load(&state[a1]);
    const f32x4 sB1 = __builtin_nontemporal_load(&state[b1]);

    const f32x4 oA0 = p00 * sA0 + p01 * sB0;
    const f32x4 oB0 = p10 * sA0 + p11 * sB0;
    const f32x4 oA1 = p00 * sA1 + p01 * sB1;
    const f32x4 oB1 = p10 * sA1 + p11 * sB1;

    __builtin_nontemporal_store(oA0, &out[a0]);
    __builtin_nontemporal_store(oB0, &out[b0]);
    __builtin_nontemporal_store(oA1, &out[a1]);
    __builtin_nontemporal_store(oB1, &out[b1]);
}

extern "C" void kernel_launch(void* const* d_in, const int* in_sizes, int n_in,
                              void* d_out, int out_size, void* d_ws, size_t ws_size,
                              hipStream_t stream) {
    const f32x4* state = (const f32x4*)d_in[0];
    const float* pauli = (const float*)d_in[1];
    f32x4*       out   = (f32x4*)d_out;

    const int nthreads = NPAIRS4 / 2;  // 4194304
    const int block = 256;
    const int grid = nthreads / block;  // 16384

    pauli_apply_kernel<<<grid, block, 0, stream>>>(state, pauli, out);
}